// Round 2
// baseline (2996.716 us; speedup 1.0000x reference)
//
#include <hip/hip_runtime.h>
#include <hip/hip_bf16.h>
#include <math.h>

// Problem constants
constexpr int B  = 4;
constexpr int S  = 2048;
constexpr int D  = 1024;
constexpr int H  = 16;
constexpr int HD = 64;   // head dim
constexpr float SCALE = 0.125f;  // 1/sqrt(64)

// ---------------------------------------------------------------------------
// K1: projection GEMM  Y = X @ W, X:[B*S, D], W:[D, D] row-major.
// Output written in head-split layout [B, H, S, HD].
// 64x64 tile, 256 threads, 4x4 per thread, fp32.
// ---------------------------------------------------------------------------
__global__ __launch_bounds__(256) void k_proj(const float* __restrict__ X,
                                              const float* __restrict__ W,
                                              float* __restrict__ Y) {
    __shared__ float As[16][65];  // [k][m]
    __shared__ float Bs[16][65];  // [k][n]
    const int bm = blockIdx.y * 64;
    const int bn = blockIdx.x * 64;
    const int tid = threadIdx.x;
    const int tm = tid >> 4, tn = tid & 15;
    float acc[4][4] = {};

    for (int k0 = 0; k0 < D; k0 += 16) {
        // X tile: rows bm..bm+63, cols k0..k0+15 (each thread one float4)
        {
            const int row = tid >> 2;
            const int kq  = (tid & 3) * 4;
            const float4 xv = *reinterpret_cast<const float4*>(
                &X[(size_t)(bm + row) * D + k0 + kq]);
            As[kq + 0][row] = xv.x;
            As[kq + 1][row] = xv.y;
            As[kq + 2][row] = xv.z;
            As[kq + 3][row] = xv.w;
        }
        // W tile: rows k0..k0+15, cols bn..bn+63
        {
            const int kr = tid >> 4;
            const int nc = (tid & 15) * 4;
            const float4 wv = *reinterpret_cast<const float4*>(
                &W[(size_t)(k0 + kr) * D + bn + nc]);
            Bs[kr][nc + 0] = wv.x;
            Bs[kr][nc + 1] = wv.y;
            Bs[kr][nc + 2] = wv.z;
            Bs[kr][nc + 3] = wv.w;
        }
        __syncthreads();
#pragma unroll
        for (int kk = 0; kk < 16; ++kk) {
            float a[4], b[4];
#pragma unroll
            for (int i = 0; i < 4; ++i) a[i] = As[kk][tm * 4 + i];
#pragma unroll
            for (int j = 0; j < 4; ++j) b[j] = Bs[kk][tn * 4 + j];
#pragma unroll
            for (int i = 0; i < 4; ++i)
#pragma unroll
                for (int j = 0; j < 4; ++j) acc[i][j] = fmaf(a[i], b[j], acc[i][j]);
        }
        __syncthreads();
    }
    // write to [B, H, S, HD]
#pragma unroll
    for (int i = 0; i < 4; ++i) {
        const int m = bm + tm * 4 + i;
        const int b = m >> 11;       // m / S
        const int s = m & (S - 1);   // m % S
#pragma unroll
        for (int j = 0; j < 4; ++j) {
            const int n = bn + tn * 4 + j;
            const int h = n >> 6;    // n / HD
            const int e = n & 63;    // n % HD
            Y[(((size_t)(b * H + h) * S) + s) * HD + e] = acc[i][j];
        }
    }
}

// ---------------------------------------------------------------------------
// K2: scores = qh @ kh^T * SCALE, + alibi, key-mask -> -1e30.
// Written to the `a` region of d_out as raw (pre-softmax) scores.
// Per (b,h): 2048x2048x64. 64x64 tiles.
// ---------------------------------------------------------------------------
__global__ __launch_bounds__(256) void k_scores(const float* __restrict__ QH,
                                                const float* __restrict__ KH,
                                                const float* __restrict__ ALIBI,
                                                const int* __restrict__ MASK,
                                                float* __restrict__ Wout) {
    const int bh = blockIdx.z;           // b*H + h
    const int b  = bh >> 4;
    const int h  = bh & 15;
    const int bq = blockIdx.y * 64;
    const int bk = blockIdx.x * 64;
    __shared__ float As[16][65];  // [e][q]
    __shared__ float Bs[16][65];  // [e][k]
    const int tid = threadIdx.x;
    const int tq = tid >> 4, tk = tid & 15;
    float acc[4][4] = {};
    const float* Qb = QH + (size_t)bh * S * HD;
    const float* Kb = KH + (size_t)bh * S * HD;

    for (int e0 = 0; e0 < HD; e0 += 16) {
        {
            const int row = tid >> 2;
            const int eq  = (tid & 3) * 4;
            const float4 qv = *reinterpret_cast<const float4*>(
                &Qb[(size_t)(bq + row) * HD + e0 + eq]);
            As[eq + 0][row] = qv.x;
            As[eq + 1][row] = qv.y;
            As[eq + 2][row] = qv.z;
            As[eq + 3][row] = qv.w;
            const float4 kv = *reinterpret_cast<const float4*>(
                &Kb[(size_t)(bk + row) * HD + e0 + eq]);
            Bs[eq + 0][row] = kv.x;
            Bs[eq + 1][row] = kv.y;
            Bs[eq + 2][row] = kv.z;
            Bs[eq + 3][row] = kv.w;
        }
        __syncthreads();
#pragma unroll
        for (int kk = 0; kk < 16; ++kk) {
            float a[4], bb[4];
#pragma unroll
            for (int i = 0; i < 4; ++i) a[i] = As[kk][tq * 4 + i];
#pragma unroll
            for (int j = 0; j < 4; ++j) bb[j] = Bs[kk][tk * 4 + j];
#pragma unroll
            for (int i = 0; i < 4; ++i)
#pragma unroll
                for (int j = 0; j < 4; ++j) acc[i][j] = fmaf(a[i], bb[j], acc[i][j]);
        }
        __syncthreads();
    }
    // epilogue: scale, mask, alibi, store raw scores
#pragma unroll
    for (int i = 0; i < 4; ++i) {
        const int qi = bq + tq * 4 + i;
        const float* arow = ALIBI + ((size_t)h * S + qi) * S;
        float* wrow = Wout + (((size_t)bh * S) + qi) * S;
#pragma unroll
        for (int j = 0; j < 4; ++j) {
            const int ki = bk + tk * 4 + j;
            const bool masked = MASK[b * S + ki] != 0;
            const float val = masked ? -1e30f : fmaf(acc[i][j], SCALE, arow[ki]);
            wrow[ki] = val;
        }
    }
}

// ---------------------------------------------------------------------------
// K3: in-place row softmax. One block (256 threads) per row of 2048.
// ---------------------------------------------------------------------------
__global__ __launch_bounds__(256) void k_softmax(float* __restrict__ A) {
    const size_t row = blockIdx.x;
    float* p = A + row * (size_t)S;
    const int tid = threadIdx.x;

    float v[8];
    float m = -INFINITY;
#pragma unroll
    for (int i = 0; i < 8; ++i) {
        v[i] = p[tid + i * 256];
        m = fmaxf(m, v[i]);
    }
    // wave (64-lane) butterfly max
#pragma unroll
    for (int off = 1; off < 64; off <<= 1) m = fmaxf(m, __shfl_xor(m, off, 64));
    __shared__ float smax[4], ssum[4];
    const int wave = tid >> 6;
    if ((tid & 63) == 0) smax[wave] = m;
    __syncthreads();
    m = fmaxf(fmaxf(smax[0], smax[1]), fmaxf(smax[2], smax[3]));

    float sum = 0.f;
#pragma unroll
    for (int i = 0; i < 8; ++i) {
        v[i] = __expf(v[i] - m);
        sum += v[i];
    }
#pragma unroll
    for (int off = 1; off < 64; off <<= 1) sum += __shfl_xor(sum, off, 64);
    if ((tid & 63) == 0) ssum[wave] = sum;
    __syncthreads();
    sum = ssum[0] + ssum[1] + ssum[2] + ssum[3];
    const float inv = 1.0f / sum;
#pragma unroll
    for (int i = 0; i < 8; ++i) p[tid + i * 256] = v[i] * inv;
}

// ---------------------------------------------------------------------------
// K4: out = a @ vh per (b,h): [2048x2048] @ [2048x64] -> [2048x64].
// Block computes 64 q-rows x full 64-col head; write combined-head layout
// out[b, s, h*64+e].
// ---------------------------------------------------------------------------
__global__ __launch_bounds__(256) void k_pv(const float* __restrict__ A,
                                            const float* __restrict__ VH,
                                            float* __restrict__ OUT) {
    const int bh = blockIdx.z;
    const int b  = bh >> 4;
    const int h  = bh & 15;
    const int bq = blockIdx.y * 64;
    __shared__ float As[16][65];  // [k][q]
    __shared__ float Bs[16][65];  // [k][e]
    const int tid = threadIdx.x;
    const int tq = tid >> 4, te = tid & 15;
    float acc[4][4] = {};
    const float* Ab = A + (size_t)bh * S * S;
    const float* Vb = VH + (size_t)bh * S * HD;

    for (int k0 = 0; k0 < S; k0 += 16) {
        {
            const int row = tid >> 2;
            const int kq  = (tid & 3) * 4;
            const float4 av = *reinterpret_cast<const float4*>(
                &Ab[(size_t)(bq + row) * S + k0 + kq]);
            As[kq + 0][row] = av.x;
            As[kq + 1][row] = av.y;
            As[kq + 2][row] = av.z;
            As[kq + 3][row] = av.w;
        }
        {
            const int kr = tid >> 4;
            const int ec = (tid & 15) * 4;
            const float4 vv = *reinterpret_cast<const float4*>(
                &Vb[(size_t)(k0 + kr) * HD + ec]);
            Bs[kr][ec + 0] = vv.x;
            Bs[kr][ec + 1] = vv.y;
            Bs[kr][ec + 2] = vv.z;
            Bs[kr][ec + 3] = vv.w;
        }
        __syncthreads();
#pragma unroll
        for (int kk = 0; kk < 16; ++kk) {
            float a[4], bb[4];
#pragma unroll
            for (int i = 0; i < 4; ++i) a[i] = As[kk][tq * 4 + i];
#pragma unroll
            for (int j = 0; j < 4; ++j) bb[j] = Bs[kk][te * 4 + j];
#pragma unroll
            for (int i = 0; i < 4; ++i)
#pragma unroll
                for (int j = 0; j < 4; ++j) acc[i][j] = fmaf(a[i], bb[j], acc[i][j]);
        }
        __syncthreads();
    }
    // OUT[b, q, h*64+e]
#pragma unroll
    for (int i = 0; i < 4; ++i) {
        const int qi = bq + tq * 4 + i;
#pragma unroll
        for (int j = 0; j < 4; ++j) {
            const int e = te * 4 + j;
            OUT[((size_t)(b * S + qi) * H + h) * HD + e] = acc[i][j];
        }
    }
}

// ---------------------------------------------------------------------------
extern "C" void kernel_launch(void* const* d_in, const int* in_sizes, int n_in,
                              void* d_out, int out_size, void* d_ws, size_t ws_size,
                              hipStream_t stream) {
    const float* q     = (const float*)d_in[0];
    const float* k     = (const float*)d_in[1];
    const float* v     = (const float*)d_in[2];
    const int*   mask  = (const int*)d_in[3];        // bool pushed as int32
    const float* alibi = (const float*)d_in[4];
    const float* Wq    = (const float*)d_in[5];
    const float* Wk    = (const float*)d_in[6];
    const float* Wv    = (const float*)d_in[7];

    float* out = (float*)d_out;                       // [B, S, D]
    float* a   = out + (size_t)B * S * D;             // [B, H, S, S]

    float* qh = (float*)d_ws;                         // [B, H, S, HD]
    float* kh = qh + (size_t)B * H * S * HD;
    float* vh = kh + (size_t)B * H * S * HD;

    const dim3 blk(256);

    // projections: M=8192 (B*S), N=1024, K=1024
    k_proj<<<dim3(D / 64, (B * S) / 64), blk, 0, stream>>>(q, Wq, qh);
    k_proj<<<dim3(D / 64, (B * S) / 64), blk, 0, stream>>>(k, Wk, kh);
    k_proj<<<dim3(D / 64, (B * S) / 64), blk, 0, stream>>>(v, Wv, vh);

    // raw scores + mask + alibi -> a region
    k_scores<<<dim3(S / 64, S / 64, B * H), blk, 0, stream>>>(qh, kh, alibi, mask, a);

    // softmax in place
    k_softmax<<<dim3(B * H * S), blk, 0, stream>>>(a);

    // PV -> out
    k_pv<<<dim3(1, S / 64, B * H), blk, 0, stream>>>(a, vh, out);
}

// Round 3
// 1715.115 us; speedup vs baseline: 1.7472x; 1.7472x over previous
//
#include <hip/hip_runtime.h>
#include <hip/hip_bf16.h>
#include <math.h>

constexpr int B  = 4;
constexpr int S  = 2048;
constexpr int D  = 1024;
constexpr int H  = 16;
constexpr int HD = 64;
constexpr float SCALE = 0.125f;  // 1/sqrt(64)

using f32x4 = __attribute__((ext_vector_type(4))) float;
using s16x8 = __attribute__((ext_vector_type(8))) short;
using u16x8 = __attribute__((ext_vector_type(8))) unsigned short;
using u16x4 = __attribute__((ext_vector_type(4))) unsigned short;

__device__ __forceinline__ unsigned short f2bf(float f) {
    union { float f; unsigned u; } x; x.f = f;
    unsigned r = x.u + 0x7fffu + ((x.u >> 16) & 1u);
    return (unsigned short)(r >> 16);
}

#define MFMA_BF16(Af, Bf, Cf) __builtin_amdgcn_mfma_f32_16x16x32_bf16(Af, Bf, Cf, 0, 0, 0)

// ---------------------------------------------------------------------------
// Transpose + convert a [D][D] fp32 weight to bf16 Wt[n][k] (k contiguous).
// ---------------------------------------------------------------------------
__global__ __launch_bounds__(256) void k_wt(const float* __restrict__ W,
                                            unsigned short* __restrict__ Wt) {
    __shared__ unsigned short T[64][68];
    const int k0 = blockIdx.x * 64, n0 = blockIdx.y * 64;
    const int t = threadIdx.x;
    {
        const int kr = t >> 4, nc4 = (t & 15) * 4;
        for (int rr = 0; rr < 4; ++rr) {
            const int kk = kr + rr * 16;
            f32x4 wv = *reinterpret_cast<const f32x4*>(&W[(size_t)(k0 + kk) * D + n0 + nc4]);
#pragma unroll
            for (int j = 0; j < 4; ++j) T[nc4 + j][kk] = f2bf(wv[j]);
        }
    }
    __syncthreads();
    {
        const int nr = t >> 4, kc4 = (t & 15) * 4;
        for (int rr = 0; rr < 4; ++rr) {
            const int nn = nr + rr * 16;
            u16x4 o;
#pragma unroll
            for (int j = 0; j < 4; ++j) o[j] = T[nn][kc4 + j];
            *reinterpret_cast<u16x4*>(&Wt[(size_t)(n0 + nn) * D + k0 + kc4]) = o;
        }
    }
}

// ---------------------------------------------------------------------------
// Projection: Y[b,h,s,e] = (X @ W)[m=(b,s), n=(h,e)], bf16 MFMA.
// 128x128 tile, BK=64, 4 waves of 64x64.
// ---------------------------------------------------------------------------
__global__ __launch_bounds__(256) void k_proj_mfma(const float* __restrict__ X,
                                                   const unsigned short* __restrict__ Wt,
                                                   unsigned short* __restrict__ Y) {
    __shared__ alignas(16) unsigned short As[128][72];  // [m][k], 144B stride
    __shared__ alignas(16) unsigned short Bs[128][72];  // [n][k]
    const int bm = blockIdx.y * 128, bn = blockIdx.x * 128;
    const int t = threadIdx.x, w = t >> 6, l = t & 63;
    const int wr = w >> 1, wc = w & 1;
    const int lr = l & 15, lg = l >> 4;
    f32x4 acc[4][4] = {};

    for (int k0 = 0; k0 < D; k0 += 64) {
        // stage A (fp32 -> bf16): 128 rows x 64 k
        {
            const int c4 = (t & 15) * 4;
            int row = t >> 4;
            for (int rr = 0; rr < 8; ++rr, row += 16) {
                f32x4 xv = *reinterpret_cast<const f32x4*>(&X[(size_t)(bm + row) * D + k0 + c4]);
                u16x4 hv;
#pragma unroll
                for (int j = 0; j < 4; ++j) hv[j] = f2bf(xv[j]);
                *reinterpret_cast<u16x4*>(&As[row][c4]) = hv;
            }
        }
        // stage B from pre-transposed bf16 Wt: 128 n-rows x 64 k
        for (int i = 0; i < 4; ++i) {
            const int idx = t + i * 256;
            const int row = idx >> 3, c8 = (idx & 7) * 8;
            *reinterpret_cast<u16x8*>(&Bs[row][c8]) =
                *reinterpret_cast<const u16x8*>(&Wt[(size_t)(bn + row) * D + k0 + c8]);
        }
        __syncthreads();
#pragma unroll
        for (int kk = 0; kk < 2; ++kk) {
            s16x8 af[4], bf[4];
#pragma unroll
            for (int f = 0; f < 4; ++f) {
                af[f] = *reinterpret_cast<const s16x8*>(&As[wr * 64 + f * 16 + lr][kk * 32 + lg * 8]);
                bf[f] = *reinterpret_cast<const s16x8*>(&Bs[wc * 64 + f * 16 + lr][kk * 32 + lg * 8]);
            }
#pragma unroll
            for (int fm = 0; fm < 4; ++fm)
#pragma unroll
                for (int fn = 0; fn < 4; ++fn)
                    acc[fm][fn] = MFMA_BF16(af[fm], bf[fn], acc[fm][fn]);
        }
        __syncthreads();
    }
    // epilogue -> Y[b,h,s,e] bf16
#pragma unroll
    for (int fm = 0; fm < 4; ++fm)
#pragma unroll
        for (int fn = 0; fn < 4; ++fn)
#pragma unroll
            for (int r = 0; r < 4; ++r) {
                const int m = bm + wr * 64 + fm * 16 + lg * 4 + r;
                const int n = bn + wc * 64 + fn * 16 + lr;
                const int b = m >> 11, s = m & (S - 1);
                const int h = n >> 6, e = n & 63;
                Y[(((size_t)(b * H + h) * S) + s) * HD + e] = f2bf(acc[fm][fn][r]);
            }
}

// ---------------------------------------------------------------------------
// Transpose vh[b,h,s,e] -> vhT[b,h,e,s] (bf16).
// ---------------------------------------------------------------------------
__global__ __launch_bounds__(256) void k_vt(const unsigned short* __restrict__ Vh,
                                            unsigned short* __restrict__ VT) {
    __shared__ alignas(16) unsigned short T[64][264];  // [e][s_local+pad]
    const int bh = blockIdx.y;
    const int s0 = blockIdx.x * 256;
    const int t = threadIdx.x;
    {
        const int e4 = (t & 15) * 4;
        int sr = t >> 4;
        for (int rr = 0; rr < 16; ++rr, sr += 16) {
            u16x4 vv = *reinterpret_cast<const u16x4*>(&Vh[((size_t)bh * S + s0 + sr) * HD + e4]);
#pragma unroll
            for (int j = 0; j < 4; ++j) T[e4 + j][sr] = vv[j];
        }
    }
    __syncthreads();
    {
        const int e = t >> 2, sl0 = (t & 3) * 64;
        for (int c = 0; c < 8; ++c) {
            u16x8 o = *reinterpret_cast<const u16x8*>(&T[e][sl0 + c * 8]);
            *reinterpret_cast<u16x8*>(&VT[((size_t)bh * HD + e) * S + s0 + sl0 + c * 8]) = o;
        }
    }
}

// ---------------------------------------------------------------------------
// Scores: a_raw[bh,q,k] = (qh . kh)*SCALE + alibi, masked -> -1e30. bf16 MFMA.
// 128q x 128k tile, single HD=64 staging, 4 waves of 64x64.
// ---------------------------------------------------------------------------
__global__ __launch_bounds__(256) void k_scores_mfma(const unsigned short* __restrict__ QH,
                                                     const unsigned short* __restrict__ KH,
                                                     const float* __restrict__ ALIBI,
                                                     const int* __restrict__ MASK,
                                                     float* __restrict__ Aout) {
    __shared__ alignas(16) unsigned short Qs[128][72];
    __shared__ alignas(16) unsigned short Ks[128][72];
    const int bh = blockIdx.z, b = bh >> 4, h = bh & 15;
    const int bq = blockIdx.y * 128, bk = blockIdx.x * 128;
    const int t = threadIdx.x, w = t >> 6, l = t & 63;
    const int wr = w >> 1, wc = w & 1;
    const int lr = l & 15, lg = l >> 4;
    const unsigned short* Qb = QH + (size_t)bh * S * HD;
    const unsigned short* Kb = KH + (size_t)bh * S * HD;

    for (int i = 0; i < 4; ++i) {
        const int idx = t + i * 256;
        const int row = idx >> 3, c8 = (idx & 7) * 8;
        *reinterpret_cast<u16x8*>(&Qs[row][c8]) =
            *reinterpret_cast<const u16x8*>(&Qb[(size_t)(bq + row) * HD + c8]);
        *reinterpret_cast<u16x8*>(&Ks[row][c8]) =
            *reinterpret_cast<const u16x8*>(&Kb[(size_t)(bk + row) * HD + c8]);
    }
    __syncthreads();

    f32x4 acc[4][4] = {};
#pragma unroll
    for (int kk = 0; kk < 2; ++kk) {
        s16x8 qf[4], kf[4];
#pragma unroll
        for (int f = 0; f < 4; ++f) {
            qf[f] = *reinterpret_cast<const s16x8*>(&Qs[wr * 64 + f * 16 + lr][kk * 32 + lg * 8]);
            kf[f] = *reinterpret_cast<const s16x8*>(&Ks[wc * 64 + f * 16 + lr][kk * 32 + lg * 8]);
        }
#pragma unroll
        for (int fm = 0; fm < 4; ++fm)
#pragma unroll
            for (int fn = 0; fn < 4; ++fn)
                acc[fm][fn] = MFMA_BF16(qf[fm], kf[fn], acc[fm][fn]);
    }

#pragma unroll
    for (int fm = 0; fm < 4; ++fm) {
#pragma unroll
        for (int r = 0; r < 4; ++r) {
            const int qi = bq + wr * 64 + fm * 16 + lg * 4 + r;
            const float* arow = ALIBI + ((size_t)h * S + qi) * S;
            float* orow = Aout + ((size_t)bh * S + qi) * S;
#pragma unroll
            for (int fn = 0; fn < 4; ++fn) {
                const int ki = bk + wc * 64 + fn * 16 + lr;
                orow[ki] = MASK[b * S + ki] ? -1e30f
                                            : fmaf(acc[fm][fn][r], SCALE, arow[ki]);
            }
        }
    }
}

// ---------------------------------------------------------------------------
// Row softmax, in place. One block per row of 2048.
// ---------------------------------------------------------------------------
__global__ __launch_bounds__(256) void k_softmax(float* __restrict__ A) {
    const size_t row = blockIdx.x;
    float* p = A + row * (size_t)S;
    const int tid = threadIdx.x;

    float v[8];
    float m = -INFINITY;
#pragma unroll
    for (int i = 0; i < 8; ++i) {
        v[i] = p[tid + i * 256];
        m = fmaxf(m, v[i]);
    }
#pragma unroll
    for (int off = 1; off < 64; off <<= 1) m = fmaxf(m, __shfl_xor(m, off, 64));
    __shared__ float smax[4], ssum[4];
    const int wave = tid >> 6;
    if ((tid & 63) == 0) smax[wave] = m;
    __syncthreads();
    m = fmaxf(fmaxf(smax[0], smax[1]), fmaxf(smax[2], smax[3]));

    float sum = 0.f;
#pragma unroll
    for (int i = 0; i < 8; ++i) {
        v[i] = __expf(v[i] - m);
        sum += v[i];
    }
#pragma unroll
    for (int off = 1; off < 64; off <<= 1) sum += __shfl_xor(sum, off, 64);
    if ((tid & 63) == 0) ssum[wave] = sum;
    __syncthreads();
    sum = ssum[0] + ssum[1] + ssum[2] + ssum[3];
    const float inv = 1.0f / sum;
#pragma unroll
    for (int i = 0; i < 8; ++i) p[tid + i * 256] = v[i] * inv;
}

// ---------------------------------------------------------------------------
// PV: out[b,q,h*64+e] = sum_kv P[bh,q,kv] * vhT[bh,e,kv]. bf16 MFMA, no LDS.
// Block: 128 q x 64 e, 4 waves of 32x64.
// ---------------------------------------------------------------------------
__global__ __launch_bounds__(256) void k_pv_mfma(const float* __restrict__ P,
                                                 const unsigned short* __restrict__ VT,
                                                 float* __restrict__ OUT) {
    const int bh = blockIdx.y, b = bh >> 4, h = bh & 15;
    const int bq = blockIdx.x * 128;
    const int t = threadIdx.x, w = t >> 6, l = t & 63;
    const int lr = l & 15, lg = l >> 4;
    const float* Pb = P + ((size_t)bh * S + bq + w * 32) * S;
    const unsigned short* Vb = VT + (size_t)bh * HD * S;
    f32x4 acc[2][4] = {};

    for (int kv = 0; kv < S; kv += 32) {
        s16x8 pf[2];
#pragma unroll
        for (int fm = 0; fm < 2; ++fm) {
            const float* pr = Pb + (size_t)(fm * 16 + lr) * S + kv + lg * 8;
            f32x4 p0 = *reinterpret_cast<const f32x4*>(pr);
            f32x4 p1 = *reinterpret_cast<const f32x4*>(pr + 4);
            union { u16x8 u; s16x8 s; } cv;
#pragma unroll
            for (int j = 0; j < 4; ++j) {
                cv.u[j]     = f2bf(p0[j]);
                cv.u[4 + j] = f2bf(p1[j]);
            }
            pf[fm] = cv.s;
        }
        s16x8 vf[4];
#pragma unroll
        for (int fn = 0; fn < 4; ++fn)
            vf[fn] = *reinterpret_cast<const s16x8*>(&Vb[(size_t)(fn * 16 + lr) * S + kv + lg * 8]);
#pragma unroll
        for (int fm = 0; fm < 2; ++fm)
#pragma unroll
            for (int fn = 0; fn < 4; ++fn)
                acc[fm][fn] = MFMA_BF16(pf[fm], vf[fn], acc[fm][fn]);
    }

#pragma unroll
    for (int fm = 0; fm < 2; ++fm)
#pragma unroll
        for (int fn = 0; fn < 4; ++fn)
#pragma unroll
            for (int r = 0; r < 4; ++r) {
                const int qi = bq + w * 32 + fm * 16 + lg * 4 + r;
                const int e = fn * 16 + lr;
                OUT[((size_t)(b * S + qi)) * D + h * HD + e] = acc[fm][fn][r];
            }
}

// ---------------------------------------------------------------------------
extern "C" void kernel_launch(void* const* d_in, const int* in_sizes, int n_in,
                              void* d_out, int out_size, void* d_ws, size_t ws_size,
                              hipStream_t stream) {
    const float* q     = (const float*)d_in[0];
    const float* k     = (const float*)d_in[1];
    const float* v     = (const float*)d_in[2];
    const int*   mask  = (const int*)d_in[3];
    const float* alibi = (const float*)d_in[4];
    const float* Wq    = (const float*)d_in[5];
    const float* Wk    = (const float*)d_in[6];
    const float* Wv    = (const float*)d_in[7];

    float* out = (float*)d_out;                 // [B,S,D]
    float* a   = out + (size_t)B * S * D;       // [B,H,S,S]

    const size_t NH = (size_t)B * H * S * HD;   // 8.4M elems
    unsigned short* qh  = (unsigned short*)d_ws;
    unsigned short* kh  = qh + NH;
    unsigned short* vh  = kh + NH;
    unsigned short* vT  = vh + NH;
    unsigned short* wqt = vT + NH;
    unsigned short* wkt = wqt + (size_t)D * D;
    unsigned short* wvt = wkt + (size_t)D * D;

    const dim3 blk(256);

    k_wt<<<dim3(D / 64, D / 64), blk, 0, stream>>>(Wq, wqt);
    k_wt<<<dim3(D / 64, D / 64), blk, 0, stream>>>(Wk, wkt);
    k_wt<<<dim3(D / 64, D / 64), blk, 0, stream>>>(Wv, wvt);

    k_proj_mfma<<<dim3(D / 128, (B * S) / 128), blk, 0, stream>>>(q, wqt, qh);
    k_proj_mfma<<<dim3(D / 128, (B * S) / 128), blk, 0, stream>>>(k, wkt, kh);
    k_proj_mfma<<<dim3(D / 128, (B * S) / 128), blk, 0, stream>>>(v, wvt, vh);

    k_vt<<<dim3(S / 256, B * H), blk, 0, stream>>>(vh, vT);

    k_scores_mfma<<<dim3(S / 128, S / 128, B * H), blk, 0, stream>>>(qh, kh, alibi, mask, a);

    k_softmax<<<dim3(B * H * S), blk, 0, stream>>>(a);

    k_pv_mfma<<<dim3(S / 128, B * H), blk, 0, stream>>>(a, vT, out);
}

// Round 4
// 1026.024 us; speedup vs baseline: 2.9207x; 1.6716x over previous
//
#include <hip/hip_runtime.h>
#include <hip/hip_bf16.h>
#include <math.h>

constexpr int B  = 4;
constexpr int S  = 2048;
constexpr int D  = 1024;
constexpr int H  = 16;
constexpr int HD = 64;
constexpr float SCALE = 0.125f;  // 1/sqrt(64)

using f32x4 = __attribute__((ext_vector_type(4))) float;
using s16x8 = __attribute__((ext_vector_type(8))) short;
using u16x8 = __attribute__((ext_vector_type(8))) unsigned short;
using u16x4 = __attribute__((ext_vector_type(4))) unsigned short;

__device__ __forceinline__ unsigned short f2bf(float f) {
    union { float f; unsigned u; } x; x.f = f;
    unsigned r = x.u + 0x7fffu + ((x.u >> 16) & 1u);
    return (unsigned short)(r >> 16);
}

#define MFMA_BF16(Af, Bf, Cf) __builtin_amdgcn_mfma_f32_16x16x32_bf16(Af, Bf, Cf, 0, 0, 0)

// ---------------------------------------------------------------------------
// Transpose + convert a [D][D] fp32 weight to bf16 Wt[n][k] (k contiguous).
// ---------------------------------------------------------------------------
__global__ __launch_bounds__(256) void k_wt(const float* __restrict__ W,
                                            unsigned short* __restrict__ Wt) {
    __shared__ unsigned short T[64][68];
    const int k0 = blockIdx.x * 64, n0 = blockIdx.y * 64;
    const int t = threadIdx.x;
    {
        const int kr = t >> 4, nc4 = (t & 15) * 4;
        for (int rr = 0; rr < 4; ++rr) {
            const int kk = kr + rr * 16;
            f32x4 wv = *reinterpret_cast<const f32x4*>(&W[(size_t)(k0 + kk) * D + n0 + nc4]);
#pragma unroll
            for (int j = 0; j < 4; ++j) T[nc4 + j][kk] = f2bf(wv[j]);
        }
    }
    __syncthreads();
    {
        const int nr = t >> 4, kc4 = (t & 15) * 4;
        for (int rr = 0; rr < 4; ++rr) {
            const int nn = nr + rr * 16;
            u16x4 o;
#pragma unroll
            for (int j = 0; j < 4; ++j) o[j] = T[nn][kc4 + j];
            *reinterpret_cast<u16x4*>(&Wt[(size_t)(n0 + nn) * D + k0 + kc4]) = o;
        }
    }
}

// ---------------------------------------------------------------------------
// Projection: Y[b,h,s,e] = (X @ W)[m=(b,s), n=(h,e)], bf16 MFMA.
// 128x128 tile, BK=64, 4 waves of 64x64.
// ---------------------------------------------------------------------------
__global__ __launch_bounds__(256) void k_proj_mfma(const float* __restrict__ X,
                                                   const unsigned short* __restrict__ Wt,
                                                   unsigned short* __restrict__ Y) {
    __shared__ alignas(16) unsigned short As[128][72];  // [m][k]
    __shared__ alignas(16) unsigned short Bs[128][72];  // [n][k]
    const int bm = blockIdx.y * 128, bn = blockIdx.x * 128;
    const int t = threadIdx.x, w = t >> 6, l = t & 63;
    const int wr = w >> 1, wc = w & 1;
    const int lr = l & 15, lg = l >> 4;
    f32x4 acc[4][4] = {};

    for (int k0 = 0; k0 < D; k0 += 64) {
        {
            const int c4 = (t & 15) * 4;
            int row = t >> 4;
            for (int rr = 0; rr < 8; ++rr, row += 16) {
                f32x4 xv = *reinterpret_cast<const f32x4*>(&X[(size_t)(bm + row) * D + k0 + c4]);
                u16x4 hv;
#pragma unroll
                for (int j = 0; j < 4; ++j) hv[j] = f2bf(xv[j]);
                *reinterpret_cast<u16x4*>(&As[row][c4]) = hv;
            }
        }
        for (int i = 0; i < 4; ++i) {
            const int idx = t + i * 256;
            const int row = idx >> 3, c8 = (idx & 7) * 8;
            *reinterpret_cast<u16x8*>(&Bs[row][c8]) =
                *reinterpret_cast<const u16x8*>(&Wt[(size_t)(bn + row) * D + k0 + c8]);
        }
        __syncthreads();
#pragma unroll
        for (int kk = 0; kk < 2; ++kk) {
            s16x8 af[4], bf[4];
#pragma unroll
            for (int f = 0; f < 4; ++f) {
                af[f] = *reinterpret_cast<const s16x8*>(&As[wr * 64 + f * 16 + lr][kk * 32 + lg * 8]);
                bf[f] = *reinterpret_cast<const s16x8*>(&Bs[wc * 64 + f * 16 + lr][kk * 32 + lg * 8]);
            }
#pragma unroll
            for (int fm = 0; fm < 4; ++fm)
#pragma unroll
                for (int fn = 0; fn < 4; ++fn)
                    acc[fm][fn] = MFMA_BF16(af[fm], bf[fn], acc[fm][fn]);
        }
        __syncthreads();
    }
#pragma unroll
    for (int fm = 0; fm < 4; ++fm)
#pragma unroll
        for (int fn = 0; fn < 4; ++fn)
#pragma unroll
            for (int r = 0; r < 4; ++r) {
                const int m = bm + wr * 64 + fm * 16 + lg * 4 + r;
                const int n = bn + wc * 64 + fn * 16 + lr;
                const int b = m >> 11, s = m & (S - 1);
                const int h = n >> 6, e = n & 63;
                Y[(((size_t)(b * H + h) * S) + s) * HD + e] = f2bf(acc[fm][fn][r]);
            }
}

// ---------------------------------------------------------------------------
// Transpose vh[b,h,s,e] -> vhT[b,h,e,s] (bf16).
// ---------------------------------------------------------------------------
__global__ __launch_bounds__(256) void k_vt(const unsigned short* __restrict__ Vh,
                                            unsigned short* __restrict__ VT) {
    __shared__ alignas(16) unsigned short T[64][264];
    const int bh = blockIdx.y;
    const int s0 = blockIdx.x * 256;
    const int t = threadIdx.x;
    {
        const int e4 = (t & 15) * 4;
        int sr = t >> 4;
        for (int rr = 0; rr < 16; ++rr, sr += 16) {
            u16x4 vv = *reinterpret_cast<const u16x4*>(&Vh[((size_t)bh * S + s0 + sr) * HD + e4]);
#pragma unroll
            for (int j = 0; j < 4; ++j) T[e4 + j][sr] = vv[j];
        }
    }
    __syncthreads();
    {
        const int e = t >> 2, sl0 = (t & 3) * 64;
        for (int c = 0; c < 8; ++c) {
            u16x8 o = *reinterpret_cast<const u16x8*>(&T[e][sl0 + c * 8]);
            *reinterpret_cast<u16x8*>(&VT[((size_t)bh * HD + e) * S + s0 + sl0 + c * 8]) = o;
        }
    }
}

// ---------------------------------------------------------------------------
// Fused scores+softmax+PV. Block: 64 q-rows of one (b,h); 4 waves x 16 rows.
// Pass 1: online (m,l) over all k-tiles. Pass 2: recompute scores,
// p = exp(s-m)/l, write `a` coalesced, accumulate PV via MFMA.
// ---------------------------------------------------------------------------
__global__ __launch_bounds__(256) void k_fused(const unsigned short* __restrict__ QH,
                                               const unsigned short* __restrict__ KH,
                                               const unsigned short* __restrict__ VT,
                                               const float* __restrict__ ALIBI,
                                               const int* __restrict__ MASK,
                                               float* __restrict__ Aout,
                                               float* __restrict__ OUT) {
    __shared__ alignas(16) unsigned short Qs[64][72];  // [q][e]
    __shared__ alignas(16) unsigned short Ks[64][72];  // [k][e]
    __shared__ alignas(16) unsigned short Vs[64][72];  // [e][kv]
    __shared__ alignas(16) float Ps[64][68];           // [q][kv] probs fp32
    __shared__ alignas(16) float ALs[64][68];          // alibi (+mask) tile

    const int bh = blockIdx.y, b = bh >> 4, h = bh & 15;
    const int q0 = blockIdx.x * 64;
    const int t = threadIdx.x, w = t >> 6, ln = t & 63;
    const int lr = ln & 15, lg = ln >> 4;

    const unsigned short* Qb = QH + (size_t)bh * S * HD;
    const unsigned short* Kb = KH + (size_t)bh * S * HD;
    const unsigned short* Vb = VT + (size_t)bh * HD * S;

    // stage Q once (64 rows x 64 e)
#pragma unroll
    for (int i = 0; i < 2; ++i) {
        const int idx = t + i * 256, row = idx >> 3, c8 = (idx & 7) * 8;
        *reinterpret_cast<u16x8*>(&Qs[row][c8]) =
            *reinterpret_cast<const u16x8*>(&Qb[(size_t)(q0 + row) * HD + c8]);
    }

    float m_[4], l_[4];
#pragma unroll
    for (int r = 0; r < 4; ++r) { m_[r] = -INFINITY; l_[r] = 0.f; }

    // ---------------- pass 1: online (m, l) ----------------
    for (int k0 = 0; k0 < S; k0 += 64) {
#pragma unroll
        for (int i = 0; i < 2; ++i) {
            const int idx = t + i * 256, row = idx >> 3, c8 = (idx & 7) * 8;
            *reinterpret_cast<u16x8*>(&Ks[row][c8]) =
                *reinterpret_cast<const u16x8*>(&Kb[(size_t)(k0 + row) * HD + c8]);
        }
        {
            const int row = t >> 2, kc = (t & 3) * 16;
            const float* ap = &ALIBI[((size_t)h * S + q0 + row) * S + k0 + kc];
            const int* mp = &MASK[b * S + k0 + kc];
#pragma unroll
            for (int j = 0; j < 4; ++j) {
                f32x4 av = *reinterpret_cast<const f32x4*>(ap + j * 4);
                int4 mv = *reinterpret_cast<const int4*>(mp + j * 4);
                f32x4 sv;
                sv[0] = mv.x ? -1e30f : av[0];
                sv[1] = mv.y ? -1e30f : av[1];
                sv[2] = mv.z ? -1e30f : av[2];
                sv[3] = mv.w ? -1e30f : av[3];
                *reinterpret_cast<f32x4*>(&ALs[row][kc + j * 4]) = sv;
            }
        }
        __syncthreads();

        f32x4 acc[4] = {};
#pragma unroll
        for (int kk = 0; kk < 2; ++kk) {
            s16x8 qf = *reinterpret_cast<const s16x8*>(&Qs[w * 16 + lr][kk * 32 + lg * 8]);
#pragma unroll
            for (int fn = 0; fn < 4; ++fn) {
                s16x8 kf = *reinterpret_cast<const s16x8*>(&Ks[fn * 16 + lr][kk * 32 + lg * 8]);
                acc[fn] = MFMA_BF16(qf, kf, acc[fn]);
            }
        }
#pragma unroll
        for (int r = 0; r < 4; ++r) {
            const int rowl = w * 16 + lg * 4 + r;
            const float sc0 = fmaf(acc[0][r], SCALE, ALs[rowl][lr]);
            const float sc1 = fmaf(acc[1][r], SCALE, ALs[rowl][16 + lr]);
            const float sc2 = fmaf(acc[2][r], SCALE, ALs[rowl][32 + lr]);
            const float sc3 = fmaf(acc[3][r], SCALE, ALs[rowl][48 + lr]);
            float rmax = fmaxf(fmaxf(sc0, sc1), fmaxf(sc2, sc3));
#pragma unroll
            for (int off = 1; off < 16; off <<= 1)
                rmax = fmaxf(rmax, __shfl_xor(rmax, off, 64));
            const float mn = fmaxf(m_[r], rmax);
            float ts = __expf(sc0 - mn) + __expf(sc1 - mn) +
                       __expf(sc2 - mn) + __expf(sc3 - mn);
#pragma unroll
            for (int off = 1; off < 16; off <<= 1)
                ts += __shfl_xor(ts, off, 64);
            l_[r] = l_[r] * __expf(m_[r] - mn) + ts;
            m_[r] = mn;
        }
        __syncthreads();
    }

    float invl[4];
#pragma unroll
    for (int r = 0; r < 4; ++r) invl[r] = 1.0f / l_[r];

    // ---------------- pass 2: P write + PV ----------------
    f32x4 oacc[4] = {};
    for (int k0 = 0; k0 < S; k0 += 64) {
#pragma unroll
        for (int i = 0; i < 2; ++i) {
            const int idx = t + i * 256, row = idx >> 3, c8 = (idx & 7) * 8;
            *reinterpret_cast<u16x8*>(&Ks[row][c8]) =
                *reinterpret_cast<const u16x8*>(&Kb[(size_t)(k0 + row) * HD + c8]);
            *reinterpret_cast<u16x8*>(&Vs[row][c8]) =
                *reinterpret_cast<const u16x8*>(&Vb[(size_t)row * S + k0 + c8]);
        }
        {
            const int row = t >> 2, kc = (t & 3) * 16;
            const float* ap = &ALIBI[((size_t)h * S + q0 + row) * S + k0 + kc];
            const int* mp = &MASK[b * S + k0 + kc];
#pragma unroll
            for (int j = 0; j < 4; ++j) {
                f32x4 av = *reinterpret_cast<const f32x4*>(ap + j * 4);
                int4 mv = *reinterpret_cast<const int4*>(mp + j * 4);
                f32x4 sv;
                sv[0] = mv.x ? -1e30f : av[0];
                sv[1] = mv.y ? -1e30f : av[1];
                sv[2] = mv.z ? -1e30f : av[2];
                sv[3] = mv.w ? -1e30f : av[3];
                *reinterpret_cast<f32x4*>(&ALs[row][kc + j * 4]) = sv;
            }
        }
        __syncthreads();

        f32x4 acc[4] = {};
#pragma unroll
        for (int kk = 0; kk < 2; ++kk) {
            s16x8 qf = *reinterpret_cast<const s16x8*>(&Qs[w * 16 + lr][kk * 32 + lg * 8]);
#pragma unroll
            for (int fn = 0; fn < 4; ++fn) {
                s16x8 kf = *reinterpret_cast<const s16x8*>(&Ks[fn * 16 + lr][kk * 32 + lg * 8]);
                acc[fn] = MFMA_BF16(qf, kf, acc[fn]);
            }
        }
#pragma unroll
        for (int r = 0; r < 4; ++r) {
            const int rowl = w * 16 + lg * 4 + r;
            Ps[rowl][lr]      = __expf(fmaf(acc[0][r], SCALE, ALs[rowl][lr])      - m_[r]) * invl[r];
            Ps[rowl][16 + lr] = __expf(fmaf(acc[1][r], SCALE, ALs[rowl][16 + lr]) - m_[r]) * invl[r];
            Ps[rowl][32 + lr] = __expf(fmaf(acc[2][r], SCALE, ALs[rowl][32 + lr]) - m_[r]) * invl[r];
            Ps[rowl][48 + lr] = __expf(fmaf(acc[3][r], SCALE, ALs[rowl][48 + lr]) - m_[r]) * invl[r];
        }
        __syncthreads();

        // coalesced `a` write from Ps
        {
            const int row = t >> 2, kc = (t & 3) * 16;
            float* op = &Aout[((size_t)bh * S + q0 + row) * S + k0 + kc];
#pragma unroll
            for (int j = 0; j < 4; ++j)
                *reinterpret_cast<f32x4*>(op + j * 4) =
                    *reinterpret_cast<const f32x4*>(&Ps[row][kc + j * 4]);
        }
        // PV accumulate
#pragma unroll
        for (int c = 0; c < 2; ++c) {
            f32x4 a0 = *reinterpret_cast<const f32x4*>(&Ps[w * 16 + lr][c * 32 + lg * 8]);
            f32x4 a1 = *reinterpret_cast<const f32x4*>(&Ps[w * 16 + lr][c * 32 + lg * 8 + 4]);
            union { u16x8 u; s16x8 s; } pa;
#pragma unroll
            for (int j = 0; j < 4; ++j) { pa.u[j] = f2bf(a0[j]); pa.u[4 + j] = f2bf(a1[j]); }
#pragma unroll
            for (int fn = 0; fn < 4; ++fn) {
                s16x8 vf = *reinterpret_cast<const s16x8*>(&Vs[fn * 16 + lr][c * 32 + lg * 8]);
                oacc[fn] = MFMA_BF16(pa.s, vf, oacc[fn]);
            }
        }
        __syncthreads();
    }

    // epilogue: out[b, q, h*64+e]
#pragma unroll
    for (int fn = 0; fn < 4; ++fn)
#pragma unroll
        for (int r = 0; r < 4; ++r)
            OUT[(size_t)(b * S + q0 + w * 16 + lg * 4 + r) * D + h * HD + fn * 16 + lr] =
                oacc[fn][r];
}

// ---------------------------------------------------------------------------
extern "C" void kernel_launch(void* const* d_in, const int* in_sizes, int n_in,
                              void* d_out, int out_size, void* d_ws, size_t ws_size,
                              hipStream_t stream) {
    const float* q     = (const float*)d_in[0];
    const float* k     = (const float*)d_in[1];
    const float* v     = (const float*)d_in[2];
    const int*   mask  = (const int*)d_in[3];
    const float* alibi = (const float*)d_in[4];
    const float* Wq    = (const float*)d_in[5];
    const float* Wk    = (const float*)d_in[6];
    const float* Wv    = (const float*)d_in[7];

    float* out = (float*)d_out;                 // [B,S,D]
    float* a   = out + (size_t)B * S * D;       // [B,H,S,S]

    const size_t NH = (size_t)B * H * S * HD;
    unsigned short* qh  = (unsigned short*)d_ws;
    unsigned short* kh  = qh + NH;
    unsigned short* vh  = kh + NH;
    unsigned short* vT  = vh + NH;
    unsigned short* wqt = vT + NH;
    unsigned short* wkt = wqt + (size_t)D * D;
    unsigned short* wvt = wkt + (size_t)D * D;

    const dim3 blk(256);

    k_wt<<<dim3(D / 64, D / 64), blk, 0, stream>>>(Wq, wqt);
    k_wt<<<dim3(D / 64, D / 64), blk, 0, stream>>>(Wk, wkt);
    k_wt<<<dim3(D / 64, D / 64), blk, 0, stream>>>(Wv, wvt);

    k_proj_mfma<<<dim3(D / 128, (B * S) / 128), blk, 0, stream>>>(q, wqt, qh);
    k_proj_mfma<<<dim3(D / 128, (B * S) / 128), blk, 0, stream>>>(k, wkt, kh);
    k_proj_mfma<<<dim3(D / 128, (B * S) / 128), blk, 0, stream>>>(v, wvt, vh);

    k_vt<<<dim3(S / 256, B * H), blk, 0, stream>>>(vh, vT);

    k_fused<<<dim3(S / 64, B * H), blk, 0, stream>>>(qh, kh, vT, alibi, mask, a, out);
}

// Round 5
// 714.306 us; speedup vs baseline: 4.1953x; 1.4364x over previous
//
#include <hip/hip_runtime.h>
#include <hip/hip_bf16.h>
#include <math.h>

constexpr int B  = 4;
constexpr int S  = 2048;
constexpr int D  = 1024;
constexpr int H  = 16;
constexpr int HD = 64;
constexpr float SCALE = 0.125f;  // 1/sqrt(64)

using f32x4 = __attribute__((ext_vector_type(4))) float;
using s16x8 = __attribute__((ext_vector_type(8))) short;
using u16x8 = __attribute__((ext_vector_type(8))) unsigned short;
using u16x4 = __attribute__((ext_vector_type(4))) unsigned short;

__device__ __forceinline__ unsigned short f2bf(float f) {
    union { float f; unsigned u; } x; x.f = f;
    unsigned r = x.u + 0x7fffu + ((x.u >> 16) & 1u);
    return (unsigned short)(r >> 16);
}
__device__ __forceinline__ float bf2f(unsigned short h) {
    union { unsigned u; float f; } x; x.u = ((unsigned)h) << 16;
    return x.f;
}

#define MFMA_BF16(Af, Bf, Cf) __builtin_amdgcn_mfma_f32_16x16x32_bf16(Af, Bf, Cf, 0, 0, 0)

// ---------------------------------------------------------------------------
// Transpose + convert a [D][D] fp32 weight to bf16 Wt[n][k] (k contiguous).
// ---------------------------------------------------------------------------
__global__ __launch_bounds__(256) void k_wt(const float* __restrict__ W,
                                            unsigned short* __restrict__ Wt) {
    __shared__ unsigned short T[64][68];
    const int k0 = blockIdx.x * 64, n0 = blockIdx.y * 64;
    const int t = threadIdx.x;
    {
        const int kr = t >> 4, nc4 = (t & 15) * 4;
        for (int rr = 0; rr < 4; ++rr) {
            const int kk = kr + rr * 16;
            f32x4 wv = *reinterpret_cast<const f32x4*>(&W[(size_t)(k0 + kk) * D + n0 + nc4]);
#pragma unroll
            for (int j = 0; j < 4; ++j) T[nc4 + j][kk] = f2bf(wv[j]);
        }
    }
    __syncthreads();
    {
        const int nr = t >> 4, kc4 = (t & 15) * 4;
        for (int rr = 0; rr < 4; ++rr) {
            const int nn = nr + rr * 16;
            u16x4 o;
#pragma unroll
            for (int j = 0; j < 4; ++j) o[j] = T[nn][kc4 + j];
            *reinterpret_cast<u16x4*>(&Wt[(size_t)(n0 + nn) * D + k0 + kc4]) = o;
        }
    }
}

// ---------------------------------------------------------------------------
// Projection: Y[b,h,s,e] = (X @ W)[m=(b,s), n=(h,e)], bf16 MFMA.
// ---------------------------------------------------------------------------
__global__ __launch_bounds__(256) void k_proj_mfma(const float* __restrict__ X,
                                                   const unsigned short* __restrict__ Wt,
                                                   unsigned short* __restrict__ Y) {
    __shared__ alignas(16) unsigned short As[128][72];
    __shared__ alignas(16) unsigned short Bs[128][72];
    const int bm = blockIdx.y * 128, bn = blockIdx.x * 128;
    const int t = threadIdx.x, w = t >> 6, l = t & 63;
    const int wr = w >> 1, wc = w & 1;
    const int lr = l & 15, lg = l >> 4;
    f32x4 acc[4][4] = {};

    for (int k0 = 0; k0 < D; k0 += 64) {
        {
            const int c4 = (t & 15) * 4;
            int row = t >> 4;
            for (int rr = 0; rr < 8; ++rr, row += 16) {
                f32x4 xv = *reinterpret_cast<const f32x4*>(&X[(size_t)(bm + row) * D + k0 + c4]);
                u16x4 hv;
#pragma unroll
                for (int j = 0; j < 4; ++j) hv[j] = f2bf(xv[j]);
                *reinterpret_cast<u16x4*>(&As[row][c4]) = hv;
            }
        }
        for (int i = 0; i < 4; ++i) {
            const int idx = t + i * 256;
            const int row = idx >> 3, c8 = (idx & 7) * 8;
            *reinterpret_cast<u16x8*>(&Bs[row][c8]) =
                *reinterpret_cast<const u16x8*>(&Wt[(size_t)(bn + row) * D + k0 + c8]);
        }
        __syncthreads();
#pragma unroll
        for (int kk = 0; kk < 2; ++kk) {
            s16x8 af[4], bf[4];
#pragma unroll
            for (int f = 0; f < 4; ++f) {
                af[f] = *reinterpret_cast<const s16x8*>(&As[wr * 64 + f * 16 + lr][kk * 32 + lg * 8]);
                bf[f] = *reinterpret_cast<const s16x8*>(&Bs[wc * 64 + f * 16 + lr][kk * 32 + lg * 8]);
            }
#pragma unroll
            for (int fm = 0; fm < 4; ++fm)
#pragma unroll
                for (int fn = 0; fn < 4; ++fn)
                    acc[fm][fn] = MFMA_BF16(af[fm], bf[fn], acc[fm][fn]);
        }
        __syncthreads();
    }
#pragma unroll
    for (int fm = 0; fm < 4; ++fm)
#pragma unroll
        for (int fn = 0; fn < 4; ++fn)
#pragma unroll
            for (int r = 0; r < 4; ++r) {
                const int m = bm + wr * 64 + fm * 16 + lg * 4 + r;
                const int n = bn + wc * 64 + fn * 16 + lr;
                const int b = m >> 11, s = m & (S - 1);
                const int h = n >> 6, e = n & 63;
                Y[(((size_t)(b * H + h) * S) + s) * HD + e] = f2bf(acc[fm][fn][r]);
            }
}

// ---------------------------------------------------------------------------
// Transpose vh[b,h,s,e] -> vhT[b,h,e,s] (bf16).
// ---------------------------------------------------------------------------
__global__ __launch_bounds__(256) void k_vt(const unsigned short* __restrict__ Vh,
                                            unsigned short* __restrict__ VT) {
    __shared__ alignas(16) unsigned short T[64][264];
    const int bh = blockIdx.y;
    const int s0 = blockIdx.x * 256;
    const int t = threadIdx.x;
    {
        const int e4 = (t & 15) * 4;
        int sr = t >> 4;
        for (int rr = 0; rr < 16; ++rr, sr += 16) {
            u16x4 vv = *reinterpret_cast<const u16x4*>(&Vh[((size_t)bh * S + s0 + sr) * HD + e4]);
#pragma unroll
            for (int j = 0; j < 4; ++j) T[e4 + j][sr] = vv[j];
        }
    }
    __syncthreads();
    {
        const int e = t >> 2, sl0 = (t & 3) * 64;
        for (int c = 0; c < 8; ++c) {
            u16x8 o = *reinterpret_cast<const u16x8*>(&T[e][sl0 + c * 8]);
            *reinterpret_cast<u16x8*>(&VT[((size_t)bh * HD + e) * S + s0 + sl0 + c * 8]) = o;
        }
    }
}

// ---------------------------------------------------------------------------
// Convert alibi [H,S,S] f32 -> bf16 (grid-stride streaming).
// ---------------------------------------------------------------------------
__global__ __launch_bounds__(256) void k_abf16(const float* __restrict__ A,
                                               unsigned short* __restrict__ O) {
    const size_t N = (size_t)H * S * S;
    const size_t stride = (size_t)gridDim.x * 256 * 8;
    for (size_t i = ((size_t)blockIdx.x * 256 + threadIdx.x) * 8; i < N; i += stride) {
        f32x4 a0 = *reinterpret_cast<const f32x4*>(&A[i]);
        f32x4 a1 = *reinterpret_cast<const f32x4*>(&A[i + 4]);
        u16x8 o;
#pragma unroll
        for (int j = 0; j < 4; ++j) { o[j] = f2bf(a0[j]); o[4 + j] = f2bf(a1[j]); }
        *reinterpret_cast<u16x8*>(&O[i]) = o;
    }
}

// ---------------------------------------------------------------------------
// Fused scores+softmax+PV, no-max online sum (m=0), 2 passes.
// Block: 128 q-rows of one (b,h), 8 waves x 16 rows, 512 threads.
// ---------------------------------------------------------------------------
template <bool ABF16>
__global__ __launch_bounds__(512, 4) void k_fused(
    const unsigned short* __restrict__ QH, const unsigned short* __restrict__ KH,
    const unsigned short* __restrict__ VT, const float* __restrict__ ALIBI,
    const unsigned short* __restrict__ ABF, const int* __restrict__ MASK,
    float* __restrict__ Aout, float* __restrict__ OUT) {
    __shared__ alignas(16) unsigned short Qs[128][72];
    __shared__ alignas(16) unsigned short Ks[64][72];
    __shared__ alignas(16) unsigned short Vs[64][72];
    __shared__ alignas(16) unsigned short ALs[128][72];
    __shared__ alignas(16) unsigned short Ps[128][72];

    const int bh = blockIdx.y, b = bh >> 4, h = bh & 15;
    const int q0 = blockIdx.x * 128;
    const int t = threadIdx.x, w = t >> 6, ln = t & 63;
    const int lr = ln & 15, lg = ln >> 4;
    const unsigned short NEGBIG = f2bf(-1e30f);

    const unsigned short* Qb = QH + (size_t)bh * S * HD;
    const unsigned short* Kb = KH + (size_t)bh * S * HD;
    const unsigned short* Vb = VT + (size_t)bh * HD * S;
    const size_t hoff = (size_t)h * S * S;

    // stage Q once (128 rows x 64 e)
#pragma unroll
    for (int i = 0; i < 2; ++i) {
        const int idx = t + i * 512, row = idx >> 3, c8 = (idx & 7) * 8;
        *reinterpret_cast<u16x8*>(&Qs[row][c8]) =
            *reinterpret_cast<const u16x8*>(&Qb[(size_t)(q0 + row) * HD + c8]);
    }
    __syncthreads();
    s16x8 qf[2];
#pragma unroll
    for (int kk = 0; kk < 2; ++kk)
        qf[kk] = *reinterpret_cast<const s16x8*>(&Qs[w * 16 + lr][kk * 32 + lg * 8]);

    float psum[4] = {0.f, 0.f, 0.f, 0.f};

    // ---------------- pass 1: row sums of exp(s) ----------------
    for (int k0 = 0; k0 < S; k0 += 64) {
        // stage K tile (64 x 64)
        {
            const int row = t >> 3, c8 = (t & 7) * 8;
            *reinterpret_cast<u16x8*>(&Ks[row][c8]) =
                *reinterpret_cast<const u16x8*>(&Kb[(size_t)(k0 + row) * HD + c8]);
        }
        // stage alibi(+mask) tile (128 x 64) bf16
#pragma unroll
        for (int i = 0; i < 2; ++i) {
            const int idx = t + i * 512, row = idx >> 3, c8 = (idx & 7) * 8;
            int4 m0 = *reinterpret_cast<const int4*>(&MASK[b * S + k0 + c8]);
            int4 m1 = *reinterpret_cast<const int4*>(&MASK[b * S + k0 + c8 + 4]);
            u16x8 av;
            if constexpr (ABF16) {
                av = *reinterpret_cast<const u16x8*>(&ABF[hoff + (size_t)(q0 + row) * S + k0 + c8]);
            } else {
                f32x4 a0 = *reinterpret_cast<const f32x4*>(&ALIBI[hoff + (size_t)(q0 + row) * S + k0 + c8]);
                f32x4 a1 = *reinterpret_cast<const f32x4*>(&ALIBI[hoff + (size_t)(q0 + row) * S + k0 + c8 + 4]);
#pragma unroll
                for (int j = 0; j < 4; ++j) { av[j] = f2bf(a0[j]); av[4 + j] = f2bf(a1[j]); }
            }
            u16x8 sv;
            sv[0] = m0.x ? NEGBIG : av[0];
            sv[1] = m0.y ? NEGBIG : av[1];
            sv[2] = m0.z ? NEGBIG : av[2];
            sv[3] = m0.w ? NEGBIG : av[3];
            sv[4] = m1.x ? NEGBIG : av[4];
            sv[5] = m1.y ? NEGBIG : av[5];
            sv[6] = m1.z ? NEGBIG : av[6];
            sv[7] = m1.w ? NEGBIG : av[7];
            *reinterpret_cast<u16x8*>(&ALs[row][c8]) = sv;
        }
        __syncthreads();

        f32x4 acc[4] = {};
#pragma unroll
        for (int kk = 0; kk < 2; ++kk)
#pragma unroll
            for (int fn = 0; fn < 4; ++fn) {
                s16x8 kf = *reinterpret_cast<const s16x8*>(&Ks[fn * 16 + lr][kk * 32 + lg * 8]);
                acc[fn] = MFMA_BF16(qf[kk], kf, acc[fn]);
            }
#pragma unroll
        for (int r = 0; r < 4; ++r) {
            const int rowl = w * 16 + lg * 4 + r;
            float s = 0.f;
#pragma unroll
            for (int fn = 0; fn < 4; ++fn)
                s += __expf(fmaf(acc[fn][r], SCALE, bf2f(ALs[rowl][fn * 16 + lr])));
            psum[r] += s;
        }
        __syncthreads();
    }

    // reduce psum over the 16 lr-lanes -> invl
    float invl[4];
#pragma unroll
    for (int r = 0; r < 4; ++r) {
        float ps = psum[r];
#pragma unroll
        for (int off = 1; off < 16; off <<= 1) ps += __shfl_xor(ps, off, 64);
        invl[r] = 1.0f / ps;
    }

    // ---------------- pass 2: P write + PV ----------------
    f32x4 oacc[4] = {};
    for (int k0 = 0; k0 < S; k0 += 64) {
        {
            const int row = t >> 3, c8 = (t & 7) * 8;
            *reinterpret_cast<u16x8*>(&Ks[row][c8]) =
                *reinterpret_cast<const u16x8*>(&Kb[(size_t)(k0 + row) * HD + c8]);
            *reinterpret_cast<u16x8*>(&Vs[row][c8]) =
                *reinterpret_cast<const u16x8*>(&Vb[(size_t)row * S + k0 + c8]);
        }
#pragma unroll
        for (int i = 0; i < 2; ++i) {
            const int idx = t + i * 512, row = idx >> 3, c8 = (idx & 7) * 8;
            int4 m0 = *reinterpret_cast<const int4*>(&MASK[b * S + k0 + c8]);
            int4 m1 = *reinterpret_cast<const int4*>(&MASK[b * S + k0 + c8 + 4]);
            u16x8 av;
            if constexpr (ABF16) {
                av = *reinterpret_cast<const u16x8*>(&ABF[hoff + (size_t)(q0 + row) * S + k0 + c8]);
            } else {
                f32x4 a0 = *reinterpret_cast<const f32x4*>(&ALIBI[hoff + (size_t)(q0 + row) * S + k0 + c8]);
                f32x4 a1 = *reinterpret_cast<const f32x4*>(&ALIBI[hoff + (size_t)(q0 + row) * S + k0 + c8 + 4]);
#pragma unroll
                for (int j = 0; j < 4; ++j) { av[j] = f2bf(a0[j]); av[4 + j] = f2bf(a1[j]); }
            }
            u16x8 sv;
            sv[0] = m0.x ? NEGBIG : av[0];
            sv[1] = m0.y ? NEGBIG : av[1];
            sv[2] = m0.z ? NEGBIG : av[2];
            sv[3] = m0.w ? NEGBIG : av[3];
            sv[4] = m1.x ? NEGBIG : av[4];
            sv[5] = m1.y ? NEGBIG : av[5];
            sv[6] = m1.z ? NEGBIG : av[6];
            sv[7] = m1.w ? NEGBIG : av[7];
            *reinterpret_cast<u16x8*>(&ALs[row][c8]) = sv;
        }
        __syncthreads();

        f32x4 acc[4] = {};
#pragma unroll
        for (int kk = 0; kk < 2; ++kk)
#pragma unroll
            for (int fn = 0; fn < 4; ++fn) {
                s16x8 kf = *reinterpret_cast<const s16x8*>(&Ks[fn * 16 + lr][kk * 32 + lg * 8]);
                acc[fn] = MFMA_BF16(qf[kk], kf, acc[fn]);
            }
#pragma unroll
        for (int r = 0; r < 4; ++r) {
            const int rowl = w * 16 + lg * 4 + r;
#pragma unroll
            for (int fn = 0; fn < 4; ++fn) {
                float p = __expf(fmaf(acc[fn][r], SCALE, bf2f(ALs[rowl][fn * 16 + lr]))) * invl[r];
                Ps[rowl][fn * 16 + lr] = f2bf(p);
            }
        }
        __syncthreads();

        // coalesced `a` write from Ps (b128 LDS reads, 2-way max)
#pragma unroll
        for (int i = 0; i < 2; ++i) {
            const int idx = t + i * 512, row = idx >> 3, sub = idx & 7;
            u16x8 pv = *reinterpret_cast<const u16x8*>(&Ps[row][sub * 8]);
            f32x4 o0, o1;
#pragma unroll
            for (int j = 0; j < 4; ++j) { o0[j] = bf2f(pv[j]); o1[j] = bf2f(pv[4 + j]); }
            float* dst = &Aout[((size_t)bh * S + q0 + row) * S + k0 + sub * 8];
            *reinterpret_cast<f32x4*>(dst) = o0;
            *reinterpret_cast<f32x4*>(dst + 4) = o1;
        }
        // PV accumulate (Ps already bf16, direct fragment reads)
#pragma unroll
        for (int c = 0; c < 2; ++c) {
            s16x8 pa = *reinterpret_cast<const s16x8*>(&Ps[w * 16 + lr][c * 32 + lg * 8]);
#pragma unroll
            for (int fn = 0; fn < 4; ++fn) {
                s16x8 vf = *reinterpret_cast<const s16x8*>(&Vs[fn * 16 + lr][c * 32 + lg * 8]);
                oacc[fn] = MFMA_BF16(pa, vf, oacc[fn]);
            }
        }
        __syncthreads();
    }

    // epilogue: out[b, q, h*64+e] (already normalized)
#pragma unroll
    for (int fn = 0; fn < 4; ++fn)
#pragma unroll
        for (int r = 0; r < 4; ++r)
            OUT[(size_t)(b * S + q0 + w * 16 + lg * 4 + r) * D + h * HD + fn * 16 + lr] =
                oacc[fn][r];
}

// ---------------------------------------------------------------------------
extern "C" void kernel_launch(void* const* d_in, const int* in_sizes, int n_in,
                              void* d_out, int out_size, void* d_ws, size_t ws_size,
                              hipStream_t stream) {
    const float* q     = (const float*)d_in[0];
    const float* k     = (const float*)d_in[1];
    const float* v     = (const float*)d_in[2];
    const int*   mask  = (const int*)d_in[3];
    const float* alibi = (const float*)d_in[4];
    const float* Wq    = (const float*)d_in[5];
    const float* Wk    = (const float*)d_in[6];
    const float* Wv    = (const float*)d_in[7];

    float* out = (float*)d_out;                 // [B,S,D]
    float* a   = out + (size_t)B * S * D;       // [B,H,S,S]

    const size_t NH = (size_t)B * H * S * HD;
    unsigned short* qh  = (unsigned short*)d_ws;
    unsigned short* kh  = qh + NH;
    unsigned short* vh  = kh + NH;
    unsigned short* vT  = vh + NH;
    unsigned short* wqt = vT + NH;
    unsigned short* wkt = wqt + (size_t)D * D;
    unsigned short* wvt = wkt + (size_t)D * D;
    unsigned short* abf = wvt + (size_t)D * D;

    const size_t need_bf16 = ((size_t)(abf - qh) + (size_t)H * S * S) * sizeof(unsigned short);
    const bool use_abf16 = ws_size >= need_bf16;

    const dim3 blk(256);

    k_wt<<<dim3(D / 64, D / 64), blk, 0, stream>>>(Wq, wqt);
    k_wt<<<dim3(D / 64, D / 64), blk, 0, stream>>>(Wk, wkt);
    k_wt<<<dim3(D / 64, D / 64), blk, 0, stream>>>(Wv, wvt);

    if (use_abf16)
        k_abf16<<<dim3(8192), blk, 0, stream>>>(alibi, abf);

    k_proj_mfma<<<dim3(D / 128, (B * S) / 128), blk, 0, stream>>>(q, wqt, qh);
    k_proj_mfma<<<dim3(D / 128, (B * S) / 128), blk, 0, stream>>>(k, wkt, kh);
    k_proj_mfma<<<dim3(D / 128, (B * S) / 128), blk, 0, stream>>>(v, wvt, vh);

    k_vt<<<dim3(S / 256, B * H), blk, 0, stream>>>(vh, vT);

    if (use_abf16)
        k_fused<true><<<dim3(S / 128, B * H), dim3(512), 0, stream>>>(
            qh, kh, vT, alibi, abf, mask, a, out);
    else
        k_fused<false><<<dim3(S / 128, B * H), dim3(512), 0, stream>>>(
            qh, kh, vT, alibi, abf, mask, a, out);
}

// Round 6
// 714.293 us; speedup vs baseline: 4.1954x; 1.0000x over previous
//
#include <hip/hip_runtime.h>
#include <hip/hip_bf16.h>
#include <math.h>

constexpr int B  = 4;
constexpr int S  = 2048;
constexpr int D  = 1024;
constexpr int H  = 16;
constexpr int HD = 64;
constexpr float SCALE = 0.125f;  // 1/sqrt(64)

using f32x4 = __attribute__((ext_vector_type(4))) float;
using s16x8 = __attribute__((ext_vector_type(8))) short;
using u16x8 = __attribute__((ext_vector_type(8))) unsigned short;
using u16x4 = __attribute__((ext_vector_type(4))) unsigned short;

__device__ __forceinline__ unsigned short f2bf(float f) {
    union { float f; unsigned u; } x; x.f = f;
    unsigned r = x.u + 0x7fffu + ((x.u >> 16) & 1u);
    return (unsigned short)(r >> 16);
}
__device__ __forceinline__ float bf2f(unsigned short h) {
    union { unsigned u; float f; } x; x.u = ((unsigned)h) << 16;
    return x.f;
}

#define MFMA_BF16(Af, Bf, Cf) __builtin_amdgcn_mfma_f32_16x16x32_bf16(Af, Bf, Cf, 0, 0, 0)

// ---------------------------------------------------------------------------
// Transpose + convert a [D][D] fp32 weight to bf16 Wt[n][k] (k contiguous).
// ---------------------------------------------------------------------------
__global__ __launch_bounds__(256) void k_wt(const float* __restrict__ W,
                                            unsigned short* __restrict__ Wt) {
    __shared__ unsigned short T[64][68];
    const int k0 = blockIdx.x * 64, n0 = blockIdx.y * 64;
    const int t = threadIdx.x;
    {
        const int kr = t >> 4, nc4 = (t & 15) * 4;
        for (int rr = 0; rr < 4; ++rr) {
            const int kk = kr + rr * 16;
            f32x4 wv = *reinterpret_cast<const f32x4*>(&W[(size_t)(k0 + kk) * D + n0 + nc4]);
#pragma unroll
            for (int j = 0; j < 4; ++j) T[nc4 + j][kk] = f2bf(wv[j]);
        }
    }
    __syncthreads();
    {
        const int nr = t >> 4, kc4 = (t & 15) * 4;
        for (int rr = 0; rr < 4; ++rr) {
            const int nn = nr + rr * 16;
            u16x4 o;
#pragma unroll
            for (int j = 0; j < 4; ++j) o[j] = T[nn][kc4 + j];
            *reinterpret_cast<u16x4*>(&Wt[(size_t)(n0 + nn) * D + k0 + kc4]) = o;
        }
    }
}

// ---------------------------------------------------------------------------
// Projection: Y[b,h,s,e] = (X @ W)[m=(b,s), n=(h,e)], bf16 MFMA.
// ---------------------------------------------------------------------------
__global__ __launch_bounds__(256) void k_proj_mfma(const float* __restrict__ X,
                                                   const unsigned short* __restrict__ Wt,
                                                   unsigned short* __restrict__ Y) {
    __shared__ alignas(16) unsigned short As[128][72];
    __shared__ alignas(16) unsigned short Bs[128][72];
    const int bm = blockIdx.y * 128, bn = blockIdx.x * 128;
    const int t = threadIdx.x, w = t >> 6, l = t & 63;
    const int wr = w >> 1, wc = w & 1;
    const int lr = l & 15, lg = l >> 4;
    f32x4 acc[4][4] = {};

    for (int k0 = 0; k0 < D; k0 += 64) {
        {
            const int c4 = (t & 15) * 4;
            int row = t >> 4;
            for (int rr = 0; rr < 8; ++rr, row += 16) {
                f32x4 xv = *reinterpret_cast<const f32x4*>(&X[(size_t)(bm + row) * D + k0 + c4]);
                u16x4 hv;
#pragma unroll
                for (int j = 0; j < 4; ++j) hv[j] = f2bf(xv[j]);
                *reinterpret_cast<u16x4*>(&As[row][c4]) = hv;
            }
        }
        for (int i = 0; i < 4; ++i) {
            const int idx = t + i * 256;
            const int row = idx >> 3, c8 = (idx & 7) * 8;
            *reinterpret_cast<u16x8*>(&Bs[row][c8]) =
                *reinterpret_cast<const u16x8*>(&Wt[(size_t)(bn + row) * D + k0 + c8]);
        }
        __syncthreads();
#pragma unroll
        for (int kk = 0; kk < 2; ++kk) {
            s16x8 af[4], bf[4];
#pragma unroll
            for (int f = 0; f < 4; ++f) {
                af[f] = *reinterpret_cast<const s16x8*>(&As[wr * 64 + f * 16 + lr][kk * 32 + lg * 8]);
                bf[f] = *reinterpret_cast<const s16x8*>(&Bs[wc * 64 + f * 16 + lr][kk * 32 + lg * 8]);
            }
#pragma unroll
            for (int fm = 0; fm < 4; ++fm)
#pragma unroll
                for (int fn = 0; fn < 4; ++fn)
                    acc[fm][fn] = MFMA_BF16(af[fm], bf[fn], acc[fm][fn]);
        }
        __syncthreads();
    }
#pragma unroll
    for (int fm = 0; fm < 4; ++fm)
#pragma unroll
        for (int fn = 0; fn < 4; ++fn)
#pragma unroll
            for (int r = 0; r < 4; ++r) {
                const int m = bm + wr * 64 + fm * 16 + lg * 4 + r;
                const int n = bn + wc * 64 + fn * 16 + lr;
                const int b = m >> 11, s = m & (S - 1);
                const int h = n >> 6, e = n & 63;
                Y[(((size_t)(b * H + h) * S) + s) * HD + e] = f2bf(acc[fm][fn][r]);
            }
}

// ---------------------------------------------------------------------------
// Transpose vh[b,h,s,e] -> vhT[b,h,e,s] (bf16).
// ---------------------------------------------------------------------------
__global__ __launch_bounds__(256) void k_vt(const unsigned short* __restrict__ Vh,
                                            unsigned short* __restrict__ VT) {
    __shared__ alignas(16) unsigned short T[64][264];
    const int bh = blockIdx.y;
    const int s0 = blockIdx.x * 256;
    const int t = threadIdx.x;
    {
        const int e4 = (t & 15) * 4;
        int sr = t >> 4;
        for (int rr = 0; rr < 16; ++rr, sr += 16) {
            u16x4 vv = *reinterpret_cast<const u16x4*>(&Vh[((size_t)bh * S + s0 + sr) * HD + e4]);
#pragma unroll
            for (int j = 0; j < 4; ++j) T[e4 + j][sr] = vv[j];
        }
    }
    __syncthreads();
    {
        const int e = t >> 2, sl0 = (t & 3) * 64;
        for (int c = 0; c < 8; ++c) {
            u16x8 o = *reinterpret_cast<const u16x8*>(&T[e][sl0 + c * 8]);
            *reinterpret_cast<u16x8*>(&VT[((size_t)bh * HD + e) * S + s0 + sl0 + c * 8]) = o;
        }
    }
}

// ---------------------------------------------------------------------------
// Convert alibi [H,S,S] f32 -> bf16 (grid-stride streaming).
// ---------------------------------------------------------------------------
__global__ __launch_bounds__(256) void k_abf16(const float* __restrict__ A,
                                               unsigned short* __restrict__ O) {
    const size_t N = (size_t)H * S * S;
    const size_t stride = (size_t)gridDim.x * 256 * 8;
    for (size_t i = ((size_t)blockIdx.x * 256 + threadIdx.x) * 8; i < N; i += stride) {
        f32x4 a0 = *reinterpret_cast<const f32x4*>(&A[i]);
        f32x4 a1 = *reinterpret_cast<const f32x4*>(&A[i + 4]);
        u16x8 o;
#pragma unroll
        for (int j = 0; j < 4; ++j) { o[j] = f2bf(a0[j]); o[4 + j] = f2bf(a1[j]); }
        *reinterpret_cast<u16x8*>(&O[i]) = o;
    }
}

// ---------------------------------------------------------------------------
// Pass 1: invl[bh, q] = 1 / sum_k exp(qk*SCALE + alibi + maskadd).
// Block: 128 q-rows of one (b,h), 8 waves x 16 rows. No max-tracking (m=0):
// scores are O(10-sigma) bounded, exp cannot overflow fp32.
// ---------------------------------------------------------------------------
template <bool ABF16>
__global__ __launch_bounds__(512, 4) void k_sumexp(
    const unsigned short* __restrict__ QH, const unsigned short* __restrict__ KH,
    const float* __restrict__ ALIBI, const unsigned short* __restrict__ ABF,
    const int* __restrict__ MASK, float* __restrict__ INVL) {
    __shared__ alignas(16) unsigned short Ks[64][72];
    __shared__ alignas(16) unsigned short ALs[128][72];

    const int bh = blockIdx.y, b = bh >> 4, h = bh & 15;
    const int q0 = blockIdx.x * 128;
    const int t = threadIdx.x, w = t >> 6, ln = t & 63;
    const int lr = ln & 15, lg = ln >> 4;

    const unsigned short* Qb = QH + (size_t)bh * S * HD;
    const unsigned short* Kb = KH + (size_t)bh * S * HD;
    const size_t hoff = (size_t)h * S * S;

    // Q fragments direct from global (row = q0 + w*16 + lr)
    s16x8 qf[2];
#pragma unroll
    for (int kk = 0; kk < 2; ++kk)
        qf[kk] = *reinterpret_cast<const s16x8*>(
            &Qb[(size_t)(q0 + w * 16 + lr) * HD + kk * 32 + lg * 8]);

    float psum[4] = {0.f, 0.f, 0.f, 0.f};

    for (int k0 = 0; k0 < S; k0 += 64) {
        {
            const int row = t >> 3, c8 = (t & 7) * 8;
            *reinterpret_cast<u16x8*>(&Ks[row][c8]) =
                *reinterpret_cast<const u16x8*>(&Kb[(size_t)(k0 + row) * HD + c8]);
        }
#pragma unroll
        for (int i = 0; i < 2; ++i) {
            const int idx = t + i * 512, row = idx >> 3, c8 = (idx & 7) * 8;
            u16x8 av;
            if constexpr (ABF16) {
                av = *reinterpret_cast<const u16x8*>(&ABF[hoff + (size_t)(q0 + row) * S + k0 + c8]);
            } else {
                f32x4 a0 = *reinterpret_cast<const f32x4*>(&ALIBI[hoff + (size_t)(q0 + row) * S + k0 + c8]);
                f32x4 a1 = *reinterpret_cast<const f32x4*>(&ALIBI[hoff + (size_t)(q0 + row) * S + k0 + c8 + 4]);
#pragma unroll
                for (int j = 0; j < 4; ++j) { av[j] = f2bf(a0[j]); av[4 + j] = f2bf(a1[j]); }
            }
            *reinterpret_cast<u16x8*>(&ALs[row][c8]) = av;
        }
        float madd[4];
#pragma unroll
        for (int fn = 0; fn < 4; ++fn)
            madd[fn] = MASK[b * S + k0 + fn * 16 + lr] ? -1e30f : 0.f;
        __syncthreads();

        f32x4 acc[4] = {};
#pragma unroll
        for (int kk = 0; kk < 2; ++kk)
#pragma unroll
            for (int fn = 0; fn < 4; ++fn) {
                s16x8 kf = *reinterpret_cast<const s16x8*>(&Ks[fn * 16 + lr][kk * 32 + lg * 8]);
                acc[fn] = MFMA_BF16(qf[kk], kf, acc[fn]);
            }
#pragma unroll
        for (int r = 0; r < 4; ++r) {
            const int rowl = w * 16 + lg * 4 + r;
            float s = 0.f;
#pragma unroll
            for (int fn = 0; fn < 4; ++fn)
                s += __expf(fmaf(acc[fn][r], SCALE, bf2f(ALs[rowl][fn * 16 + lr]) + madd[fn]));
            psum[r] += s;
        }
        __syncthreads();
    }

#pragma unroll
    for (int r = 0; r < 4; ++r) {
        float ps = psum[r];
#pragma unroll
        for (int off = 1; off < 16; off <<= 1) ps += __shfl_xor(ps, off, 64);
        if (lr == 0)
            INVL[(size_t)bh * S + q0 + w * 16 + lg * 4 + r] = 1.0f / ps;
    }
}

// ---------------------------------------------------------------------------
// Pass 2: p = exp(s)*invl -> write `a` (f32) + PV accumulate -> out.
// Block: 128 q-rows of one (b,h), 8 waves x 16 rows.
// ---------------------------------------------------------------------------
template <bool ABF16>
__global__ __launch_bounds__(512, 2) void k_attn(
    const unsigned short* __restrict__ QH, const unsigned short* __restrict__ KH,
    const unsigned short* __restrict__ VT, const float* __restrict__ ALIBI,
    const unsigned short* __restrict__ ABF, const int* __restrict__ MASK,
    const float* __restrict__ INVL, float* __restrict__ Aout,
    float* __restrict__ OUT) {
    __shared__ alignas(16) unsigned short Ps[128][72];
    __shared__ alignas(16) unsigned short Ks[64][72];
    __shared__ alignas(16) unsigned short Vs[64][72];
    __shared__ alignas(16) unsigned short ALs[128][72];

    const int bh = blockIdx.y, b = bh >> 4, h = bh & 15;
    const int q0 = blockIdx.x * 128;
    const int t = threadIdx.x, w = t >> 6, ln = t & 63;
    const int lr = ln & 15, lg = ln >> 4;

    const unsigned short* Qb = QH + (size_t)bh * S * HD;
    const unsigned short* Kb = KH + (size_t)bh * S * HD;
    const unsigned short* Vb = VT + (size_t)bh * HD * S;
    const size_t hoff = (size_t)h * S * S;

    s16x8 qf[2];
#pragma unroll
    for (int kk = 0; kk < 2; ++kk)
        qf[kk] = *reinterpret_cast<const s16x8*>(
            &Qb[(size_t)(q0 + w * 16 + lr) * HD + kk * 32 + lg * 8]);

    float invl[4];
#pragma unroll
    for (int r = 0; r < 4; ++r)
        invl[r] = INVL[(size_t)bh * S + q0 + w * 16 + lg * 4 + r];

    f32x4 oacc[4] = {};
    for (int k0 = 0; k0 < S; k0 += 64) {
        {
            const int row = t >> 3, c8 = (t & 7) * 8;
            *reinterpret_cast<u16x8*>(&Ks[row][c8]) =
                *reinterpret_cast<const u16x8*>(&Kb[(size_t)(k0 + row) * HD + c8]);
            *reinterpret_cast<u16x8*>(&Vs[row][c8]) =
                *reinterpret_cast<const u16x8*>(&Vb[(size_t)row * S + k0 + c8]);
        }
#pragma unroll
        for (int i = 0; i < 2; ++i) {
            const int idx = t + i * 512, row = idx >> 3, c8 = (idx & 7) * 8;
            u16x8 av;
            if constexpr (ABF16) {
                av = *reinterpret_cast<const u16x8*>(&ABF[hoff + (size_t)(q0 + row) * S + k0 + c8]);
            } else {
                f32x4 a0 = *reinterpret_cast<const f32x4*>(&ALIBI[hoff + (size_t)(q0 + row) * S + k0 + c8]);
                f32x4 a1 = *reinterpret_cast<const f32x4*>(&ALIBI[hoff + (size_t)(q0 + row) * S + k0 + c8 + 4]);
#pragma unroll
                for (int j = 0; j < 4; ++j) { av[j] = f2bf(a0[j]); av[4 + j] = f2bf(a1[j]); }
            }
            *reinterpret_cast<u16x8*>(&ALs[row][c8]) = av;
        }
        float madd[4];
#pragma unroll
        for (int fn = 0; fn < 4; ++fn)
            madd[fn] = MASK[b * S + k0 + fn * 16 + lr] ? -1e30f : 0.f;
        __syncthreads();

        f32x4 acc[4] = {};
#pragma unroll
        for (int kk = 0; kk < 2; ++kk)
#pragma unroll
            for (int fn = 0; fn < 4; ++fn) {
                s16x8 kf = *reinterpret_cast<const s16x8*>(&Ks[fn * 16 + lr][kk * 32 + lg * 8]);
                acc[fn] = MFMA_BF16(qf[kk], kf, acc[fn]);
            }
#pragma unroll
        for (int r = 0; r < 4; ++r) {
            const int rowl = w * 16 + lg * 4 + r;
#pragma unroll
            for (int fn = 0; fn < 4; ++fn) {
                float p = __expf(fmaf(acc[fn][r], SCALE,
                                      bf2f(ALs[rowl][fn * 16 + lr]) + madd[fn])) * invl[r];
                Ps[rowl][fn * 16 + lr] = f2bf(p);
            }
        }
        __syncthreads();

        // coalesced `a` write from Ps
#pragma unroll
        for (int i = 0; i < 2; ++i) {
            const int idx = t + i * 512, row = idx >> 3, sub = idx & 7;
            u16x8 pv = *reinterpret_cast<const u16x8*>(&Ps[row][sub * 8]);
            f32x4 o0, o1;
#pragma unroll
            for (int j = 0; j < 4; ++j) { o0[j] = bf2f(pv[j]); o1[j] = bf2f(pv[4 + j]); }
            float* dst = &Aout[((size_t)bh * S + q0 + row) * S + k0 + sub * 8];
            *reinterpret_cast<f32x4*>(dst) = o0;
            *reinterpret_cast<f32x4*>(dst + 4) = o1;
        }
        // PV accumulate
#pragma unroll
        for (int c = 0; c < 2; ++c) {
            s16x8 pa = *reinterpret_cast<const s16x8*>(&Ps[w * 16 + lr][c * 32 + lg * 8]);
#pragma unroll
            for (int fn = 0; fn < 4; ++fn) {
                s16x8 vf = *reinterpret_cast<const s16x8*>(&Vs[fn * 16 + lr][c * 32 + lg * 8]);
                oacc[fn] = MFMA_BF16(pa, vf, oacc[fn]);
            }
        }
        __syncthreads();
    }

#pragma unroll
    for (int fn = 0; fn < 4; ++fn)
#pragma unroll
        for (int r = 0; r < 4; ++r)
            OUT[(size_t)(b * S + q0 + w * 16 + lg * 4 + r) * D + h * HD + fn * 16 + lr] =
                oacc[fn][r];
}

// ---------------------------------------------------------------------------
extern "C" void kernel_launch(void* const* d_in, const int* in_sizes, int n_in,
                              void* d_out, int out_size, void* d_ws, size_t ws_size,
                              hipStream_t stream) {
    const float* q     = (const float*)d_in[0];
    const float* k     = (const float*)d_in[1];
    const float* v     = (const float*)d_in[2];
    const int*   mask  = (const int*)d_in[3];
    const float* alibi = (const float*)d_in[4];
    const float* Wq    = (const float*)d_in[5];
    const float* Wk    = (const float*)d_in[6];
    const float* Wv    = (const float*)d_in[7];

    float* out = (float*)d_out;                 // [B,S,D]
    float* a   = out + (size_t)B * S * D;       // [B,H,S,S]

    const size_t NH = (size_t)B * H * S * HD;
    unsigned short* qh  = (unsigned short*)d_ws;
    unsigned short* kh  = qh + NH;
    unsigned short* vh  = kh + NH;
    unsigned short* vT  = vh + NH;
    unsigned short* wqt = vT + NH;
    unsigned short* wkt = wqt + (size_t)D * D;
    unsigned short* wvt = wkt + (size_t)D * D;
    float*          invl = (float*)(wvt + (size_t)D * D);         // [B*H*S]
    unsigned short* abf  = (unsigned short*)(invl + (size_t)B * H * S);

    const size_t need_bf16 =
        ((size_t)((unsigned short*)abf - qh) + (size_t)H * S * S) * sizeof(unsigned short);
    const bool use_abf16 = ws_size >= need_bf16;

    const dim3 blk(256);

    k_wt<<<dim3(D / 64, D / 64), blk, 0, stream>>>(Wq, wqt);
    k_wt<<<dim3(D / 64, D / 64), blk, 0, stream>>>(Wk, wkt);
    k_wt<<<dim3(D / 64, D / 64), blk, 0, stream>>>(Wv, wvt);

    if (use_abf16)
        k_abf16<<<dim3(8192), blk, 0, stream>>>(alibi, abf);

    k_proj_mfma<<<dim3(D / 128, (B * S) / 128), blk, 0, stream>>>(q, wqt, qh);
    k_proj_mfma<<<dim3(D / 128, (B * S) / 128), blk, 0, stream>>>(k, wkt, kh);
    k_proj_mfma<<<dim3(D / 128, (B * S) / 128), blk, 0, stream>>>(v, wvt, vh);

    k_vt<<<dim3(S / 256, B * H), blk, 0, stream>>>(vh, vT);

    if (use_abf16) {
        k_sumexp<true><<<dim3(S / 128, B * H), dim3(512), 0, stream>>>(
            qh, kh, alibi, abf, mask, invl);
        k_attn<true><<<dim3(S / 128, B * H), dim3(512), 0, stream>>>(
            qh, kh, vT, alibi, abf, mask, invl, a, out);
    } else {
        k_sumexp<false><<<dim3(S / 128, B * H), dim3(512), 0, stream>>>(
            qh, kh, alibi, abf, mask, invl);
        k_attn<false><<<dim3(S / 128, B * H), dim3(512), 0, stream>>>(
            qh, kh, vT, alibi, abf, mask, invl, a, out);
    }
}